// Round 1
// baseline (328.231 us; speedup 1.0000x reference)
//
#include <hip/hip_runtime.h>

#define S_    2048
#define N_    16
#define OBS_  8
#define PRED_ 12
#define B_    (S_*N_)

__device__ __forceinline__ float4 ld4(const float* p) { return *(const float4*)p; }
__device__ __forceinline__ float sigmf(float x) { return __builtin_amdgcn_rcpf(1.0f + __expf(-x)); }
__device__ __forceinline__ float tanhx(float x) { return fmaf(-2.0f, __builtin_amdgcn_rcpf(1.0f + __expf(2.0f*x)), 1.0f); }

__device__ __forceinline__ float dot16w(const float* w, const float4 x0, const float4 x1,
                                        const float4 x2, const float4 x3) {
  float4 w0 = ld4(w); float4 w1 = ld4(w+4); float4 w2 = ld4(w+8); float4 w3 = ld4(w+12);
  float a = x0.x*w0.x + x0.y*w0.y + x0.z*w0.z + x0.w*w0.w;
  float b = x1.x*w1.x + x1.y*w1.y + x1.z*w1.z + x1.w*w1.w;
  float c = x2.x*w2.x + x2.y*w2.y + x2.z*w2.z + x2.w*w2.w;
  float d = x3.x*w3.x + x3.y*w3.y + x3.z*w3.z + x3.w*w3.w;
  return (a+b)+(c+d);
}

// one scene per block; thread (i = agent, k = hidden unit), 256 threads
extern "C" __global__ __launch_bounds__(256, 3) void traj_ar_kernel(
    const float* __restrict__ traj_rel, const float* __restrict__ obs_pos,
    const int*  __restrict__ nei,       const float* __restrict__ noise,
    const float* __restrict__ eeW, const float* __restrict__ eeb,
    const float* __restrict__ eWi, const float* __restrict__ eWh, const float* __restrict__ eb,
    const float* __restrict__ diW, const float* __restrict__ dib,
    const float* __restrict__ dWi, const float* __restrict__ dWh, const float* __restrict__ db,
    const float* __restrict__ prW, const float* __restrict__ prb,
    const float* __restrict__ mW,  const float* __restrict__ mb,
    const float* __restrict__ oW,  const float* __restrict__ ob,
    float* __restrict__ out)
{
  // weights: LSTM mats transposed, row stride 20 floats (80B: b128-aligned, 2-way bank alias = free)
  __shared__ __align__(16) float sW_ee[32];
  __shared__ __align__(16) float sb_ee[16];
  __shared__ __align__(16) float sW_eiT[64*20];
  __shared__ __align__(16) float sW_ehT[64*20];
  __shared__ __align__(16) float sb_e[64];
  __shared__ __align__(16) float sW_diT[16*20];   // 18 rows used of stride 20
  __shared__ __align__(16) float sb_di[16];
  __shared__ __align__(16) float sW_dWiT[64*20];
  __shared__ __align__(16) float sW_dWhT[64*20];
  __shared__ __align__(16) float sb_d[64];
  __shared__ __align__(16) float sW_pr[32];
  __shared__ __align__(16) float sb_pr[16];
  __shared__ __align__(16) float sW_o[64];
  __shared__ __align__(16) float sb_o[4];
  // state
  __shared__ __align__(16) float h_s[2][256];
  __shared__ __align__(16) float e_s[256];
  __shared__ __align__(16) float ctx_s[256];
  __shared__ __align__(16) float hW_s[256];
  __shared__ __align__(16) float re_s[16*260];    // [i*260 + j*16 + m]; i-stride pad kills read conflicts
  __shared__ __align__(16) float pos_s[32];
  __shared__ __align__(16) float prev_s[32];

  const int tid = threadIdx.x;
  const int s = blockIdx.x;
  const int i = tid >> 4;
  const int k = tid & 15;
  const int bi = s*N_ + i;

  // ---- stage weights into LDS ----
  if (tid < 32) sW_ee[tid] = eeW[tid];
  if (tid < 16) sb_ee[tid] = eeb[tid];
  for (int idx = tid; idx < 1024; idx += 256) {
    int m = idx >> 6, c = idx & 63;
    sW_eiT[c*20+m] = eWi[idx];
    sW_ehT[c*20+m] = eWh[idx];
    sW_dWiT[c*20+m] = dWi[idx];
    sW_dWhT[c*20+m] = dWh[idx];
  }
  if (tid < 64) sb_e[tid] = eb[tid];
  for (int idx = tid; idx < 288; idx += 256) { int m = idx >> 4, c = idx & 15; sW_diT[c*20+m] = diW[idx]; }
  if (tid < 16) sb_di[tid] = dib[tid];
  if (tid < 64) sb_d[tid] = db[tid];
  if (tid < 32) sW_pr[tid] = prW[tid];
  if (tid < 16) sb_pr[tid] = prb[tid];
  if (tid < 64) sW_o[tid] = oW[tid];
  if (tid < 4)  sb_o[tid] = ob[tid];

  h_s[0][tid] = 0.0f;
  ctx_s[tid] = 0.0f;
  if (k < 2) {
    prev_s[i*2+k] = traj_rel[((OBS_-1)*B_ + bi)*2 + k];  // out init = traj_rel[OBS-1]
    pos_s[i*2+k]  = obs_pos[((OBS_-1)*B_ + bi)*2 + k];   // pos init = obs_traj_pos[-1]
  }

  // pool-MLP column k lives in registers (32 floats); all blocks hit same L1 lines
  float wm[32];
  #pragma unroll
  for (int m = 0; m < 32; ++m) wm[m] = mW[m*16 + k];
  const float bmlp = mb[k];

  // time-invariant neighbor mask -> register bitmask via wave ballot
  unsigned long long bal = __ballot(nei[bi*N_ + k] > 0);
  const unsigned mbits = (unsigned)((bal >> (16*(i & 3))) & 0xFFFFull);
  const bool has = (mbits != 0);

  __syncthreads();

  // ---- encoder: 8 LSTM steps ----
  int cur = 0;
  float c_reg = 0.0f;
  const float2* xr2 = (const float2*)traj_rel;
  for (int t = 0; t < OBS_; ++t) {
    float2 x = xr2[t*B_ + bi];
    float em[16];
    #pragma unroll
    for (int m = 0; m < 16; ++m)
      em[m] = fmaxf(fmaf(x.y, sW_ee[16+m], fmaf(x.x, sW_ee[m], sb_ee[m])), 0.0f);
    float4 e0 = make_float4(em[0],em[1],em[2],em[3]);
    float4 e1 = make_float4(em[4],em[5],em[6],em[7]);
    float4 e2 = make_float4(em[8],em[9],em[10],em[11]);
    float4 e3 = make_float4(em[12],em[13],em[14],em[15]);
    const float* hp = &h_s[cur][i*16];
    float4 h0 = ld4(hp), h1 = ld4(hp+4), h2 = ld4(hp+8), h3 = ld4(hp+12);
    float g0 = sb_e[k]    + dot16w(&sW_eiT[(k)*20],    e0,e1,e2,e3) + dot16w(&sW_ehT[(k)*20],    h0,h1,h2,h3);
    float g1 = sb_e[k+16] + dot16w(&sW_eiT[(k+16)*20], e0,e1,e2,e3) + dot16w(&sW_ehT[(k+16)*20], h0,h1,h2,h3);
    float g2 = sb_e[k+32] + dot16w(&sW_eiT[(k+32)*20], e0,e1,e2,e3) + dot16w(&sW_ehT[(k+32)*20], h0,h1,h2,h3);
    float g3 = sb_e[k+48] + dot16w(&sW_eiT[(k+48)*20], e0,e1,e2,e3) + dot16w(&sW_ehT[(k+48)*20], h0,h1,h2,h3);
    float ig = sigmf(g0), fg = sigmf(g1), gv = tanhx(g2), og = sigmf(g3);
    c_reg = fg*c_reg + ig*gv;
    float nh = og * tanhx(c_reg);
    h_s[cur^1][i*16+k] = nh;   // write other buffer: no read/write race
    __syncthreads();
    cur ^= 1;
  }

  // ---- decoder: 12 autoregressive steps ----
  c_reg = 0.0f;                       // decoder c starts at zero
  const int MU_OFF = PRED_*B_*2;
  const int SD_OFF = 2*PRED_*B_*2;
  for (int t = 0; t < PRED_; ++t) {
    // phase 1: e = relu([ctx, prev] @ dec_in_W + b)
    {
      const float* cx = &ctx_s[i*16];
      float4 c0 = ld4(cx), c1 = ld4(cx+4), c2 = ld4(cx+8), c3 = ld4(cx+12);
      float p0 = prev_s[i*2+0], p1 = prev_s[i*2+1];
      const float* wd = &sW_diT[k*20];
      float acc = sb_di[k] + dot16w(wd, c0,c1,c2,c3) + p0*wd[16] + p1*wd[17];
      e_s[i*16+k] = fmaxf(acc, 0.0f);
    }
    __syncthreads(); // A
    // phase 2: LSTM cell
    {
      const float* ep = &e_s[i*16];
      float4 e0 = ld4(ep), e1 = ld4(ep+4), e2 = ld4(ep+8), e3 = ld4(ep+12);
      const float* hp = &h_s[cur][i*16];
      float4 h0 = ld4(hp), h1 = ld4(hp+4), h2 = ld4(hp+8), h3 = ld4(hp+12);
      float g0 = sb_d[k]    + dot16w(&sW_dWiT[(k)*20],    e0,e1,e2,e3) + dot16w(&sW_dWhT[(k)*20],    h0,h1,h2,h3);
      float g1 = sb_d[k+16] + dot16w(&sW_dWiT[(k+16)*20], e0,e1,e2,e3) + dot16w(&sW_dWhT[(k+16)*20], h0,h1,h2,h3);
      float g2 = sb_d[k+32] + dot16w(&sW_dWiT[(k+32)*20], e0,e1,e2,e3) + dot16w(&sW_dWhT[(k+32)*20], h0,h1,h2,h3);
      float g3 = sb_d[k+48] + dot16w(&sW_dWiT[(k+48)*20], e0,e1,e2,e3) + dot16w(&sW_dWhT[(k+48)*20], h0,h1,h2,h3);
      float ig = sigmf(g0), fg = sigmf(g1), gv = tanhx(g2), og = sigmf(g3);
      c_reg = fg*c_reg + ig*gv;
      float nh = og * tanhx(c_reg);
      h_s[cur^1][i*16+k] = nh;
    }
    __syncthreads(); // B
    cur ^= 1;
    // phase 3: (a) hW[j][k] = h[j] . Wmlp[16:32, k]  (this thread's i plays the j role)
    //          (b) re[i][j][:] embedding (this thread: a=i, j=k)
    {
      const float* hj = &h_s[cur][i*16];
      float hw = 0.0f;
      #pragma unroll
      for (int m = 0; m < 16; ++m) hw = fmaf(hj[m], wm[16+m], hw);
      hW_s[i*16+k] = hw;

      float rx = pos_s[i*2+0] - pos_s[k*2+0];
      float ry = pos_s[i*2+1] - pos_s[k*2+1];
      float rv[16];
      #pragma unroll
      for (int m = 0; m < 16; ++m)
        rv[m] = fmaxf(fmaf(ry, sW_pr[16+m], fmaf(rx, sW_pr[m], sb_pr[m])), 0.0f);
      float* rp = &re_s[i*260 + k*16];
      *(float4*)(rp+0)  = make_float4(rv[0],rv[1],rv[2],rv[3]);
      *(float4*)(rp+4)  = make_float4(rv[4],rv[5],rv[6],rv[7]);
      *(float4*)(rp+8)  = make_float4(rv[8],rv[9],rv[10],rv[11]);
      *(float4*)(rp+12) = make_float4(rv[12],rv[13],rv[14],rv[15]);
    }
    __syncthreads(); // C
    // phase 4: masked max-pool over neighbors j
    {
      float pooled = -1e30f;
      const float* rb = &re_s[i*260];
      #pragma unroll
      for (int j = 0; j < 16; ++j) {
        const float* rp = rb + j*16;
        float4 r0 = ld4(rp), r1 = ld4(rp+4), r2 = ld4(rp+8), r3 = ld4(rp+12);
        float acc = bmlp + hW_s[j*16+k];
        acc += r0.x*wm[0]  + r0.y*wm[1]  + r0.z*wm[2]  + r0.w*wm[3]
             + r1.x*wm[4]  + r1.y*wm[5]  + r1.z*wm[6]  + r1.w*wm[7]
             + r2.x*wm[8]  + r2.y*wm[9]  + r2.z*wm[10] + r2.w*wm[11]
             + r3.x*wm[12] + r3.y*wm[13] + r3.z*wm[14] + r3.w*wm[15];
        float feat = fmaxf(acc, 0.0f);
        if ((mbits >> j) & 1u) pooled = fmaxf(pooled, feat);
      }
      ctx_s[i*16+k] = has ? pooled : 0.0f;
    }
    __syncthreads(); // D
    // phase 5+6: o4 = (h+ctx)@out_W + b; mu/std/pred; write outputs; advance pos
    {
      float o4v = 0.0f;
      if (k < 4) {
        const float* hp = &h_s[cur][i*16];
        const float* cx = &ctx_s[i*16];
        float acc = sb_o[k];
        #pragma unroll
        for (int m = 0; m < 16; ++m) acc = fmaf(hp[m]+cx[m], sW_o[m*4+k], acc);
        o4v = acc;
      }
      float sc = __shfl_down(o4v, 2, 64);   // lane k<2 grabs o4[2+k]
      if (k < 2) {
        float mu = o4v;
        float scale = fminf(fmaxf(sc, -9.0f), 4.0f);
        float sd = __expf(scale);
        float nz = noise[(t*B_ + bi)*2 + k];
        float pr = fmaf(sd, nz, mu);
        int o = (t*B_ + bi)*2 + k;
        out[o]          = pr;
        out[MU_OFF + o] = mu;
        out[SD_OFF + o] = sd;
        pos_s[i*2+k] += pr;
        prev_s[i*2+k] = pr;
      }
    }
    __syncthreads(); // E
  }
}

extern "C" void kernel_launch(void* const* d_in, const int* in_sizes, int n_in,
                              void* d_out, int out_size, void* d_ws, size_t ws_size,
                              hipStream_t stream) {
  (void)in_sizes; (void)n_in; (void)d_ws; (void)ws_size; (void)out_size;
  traj_ar_kernel<<<dim3(S_), dim3(256), 0, stream>>>(
      (const float*)d_in[0],  (const float*)d_in[1],  (const int*)d_in[2],   (const float*)d_in[3],
      (const float*)d_in[4],  (const float*)d_in[5],  (const float*)d_in[6], (const float*)d_in[7],
      (const float*)d_in[8],  (const float*)d_in[9],  (const float*)d_in[10],(const float*)d_in[11],
      (const float*)d_in[12], (const float*)d_in[13], (const float*)d_in[14],(const float*)d_in[15],
      (const float*)d_in[16], (const float*)d_in[17], (const float*)d_in[18],(const float*)d_in[19],
      (float*)d_out);
}